// Round 6
// baseline (232.719 us; speedup 1.0000x reference)
//
#include <hip/hip_runtime.h>
#include <hip/hip_bf16.h>
#include <math.h>

#define NPTS   500000
#define NB     256
#define TOPK   10
#define CAP    2048        // per-query candidate cap in k_final
#define SBLK   1024        // sample slices
#define SPER   16          // points per slice -> 16384-pt sample
#define MARGIN 2.0f        // bf16 worst-case score err ~0.5; 4x headroom
#define FBLK   1280        // k_filter grid = 5 blocks/CU (cap for launch_bounds(256,5))
#define NCHUNK 3907        // ceil(NPTS/128)
#define LCAP   8           // per-(block,query) local cap; overflow safe-path
#define PMAIN  393216      // main pair region (dwords) < 2^20
#define OCAP   32768       // overflow pair region (dwords)

typedef short v4s  __attribute__((ext_vector_type(4)));
typedef short v8s  __attribute__((ext_vector_type(8)));
typedef float v16f __attribute__((ext_vector_type(16)));

__device__ __forceinline__ unsigned short f2bf(float f) {   // RNE
    unsigned u = __float_as_uint(f);
    unsigned r = u + 0x7FFFu + ((u >> 16) & 1u);
    return (unsigned short)(r >> 16);
}
__device__ __forceinline__ float bf2f(unsigned short h) {
    return __uint_as_float(((unsigned)h) << 16);
}

// async 16-B global->LDS (wave-uniform base + lane*16 contiguous pattern)
__device__ __forceinline__ void async_copy16(void* lds, const void* g) {
    __builtin_amdgcn_global_load_lds(
        (const __attribute__((address_space(1))) unsigned*)g,
        (__attribute__((address_space(3))) unsigned*)lds, 16, 0, 0);
}

// --- exact fp32 pieces: bitwise-identical order in k_sample and k_final -----
__device__ __forceinline__ float norm34(const float* __restrict__ r) {
    float a0 = 0.f, a1 = 0.f, a2 = 0.f, a3 = 0.f;
#pragma unroll
    for (int d = 0; d < 32; d += 4) {
        a0 = fmaf(r[d + 0], r[d + 0], a0);
        a1 = fmaf(r[d + 1], r[d + 1], a1);
        a2 = fmaf(r[d + 2], r[d + 2], a2);
        a3 = fmaf(r[d + 3], r[d + 3], a3);
    }
    a0 = fmaf(r[32], r[32], a0);
    a1 = fmaf(r[33], r[33], a1);
    return (a0 + a1) + (a2 + a3);
}
__device__ __forceinline__ float dot34(const float* __restrict__ r, const float* q) {
    float a0 = 0.f, a1 = 0.f, a2 = 0.f, a3 = 0.f;
#pragma unroll
    for (int d = 0; d < 32; d += 4) {
        a0 = fmaf(r[d + 0], q[d + 0], a0);
        a1 = fmaf(r[d + 1], q[d + 1], a1);
        a2 = fmaf(r[d + 2], q[d + 2], a2);
        a3 = fmaf(r[d + 3], q[d + 3], a3);
    }
    a0 = fmaf(r[32], q[32], a0);
    a1 = fmaf(r[33], q[33], a1);
    return (a0 + a1) + (a2 + a3);
}
// float4 LDS variant, IDENTICAL fma order -> bitwise-equal s
__device__ __forceinline__ float dot34_v4(const float4* __restrict__ r4, const float* q) {
    float a0 = 0.f, a1 = 0.f, a2 = 0.f, a3 = 0.f;
#pragma unroll
    for (int dp = 0; dp < 8; ++dp) {
        float4 v = r4[dp];
        a0 = fmaf(v.x, q[4 * dp + 0], a0);
        a1 = fmaf(v.y, q[4 * dp + 1], a1);
        a2 = fmaf(v.z, q[4 * dp + 2], a2);
        a3 = fmaf(v.w, q[4 * dp + 3], a3);
    }
    float2 t = *(const float2*)(r4 + 8);
    a0 = fmaf(t.x, q[32], a0);
    a1 = fmaf(t.y, q[33], a1);
    return (a0 + a1) + (a2 + a3);
}
__device__ __forceinline__ void load_q(const float* __restrict__ obs,
                                       const float* __restrict__ act, int b, float* q) {
#pragma unroll
    for (int d = 0; d < 32; ++d) q[d] = obs[b * 32 + d];
    q[32] = act[b * 2 + 0];
    q[33] = act[b * 2 + 1];
}

// --- kernel 0a: per-(query, 16-pt slice) min of s; minima transposed --------
__global__ __launch_bounds__(256, 4) void k_sample(const float* __restrict__ obs,
                                                   const float* __restrict__ act,
                                                   const float* __restrict__ msa,
                                                   float* __restrict__ minima) {
    __shared__ __align__(16) float sm[SPER * 36];
    __shared__ float smn[SPER];
    const int g = blockIdx.x, t = threadIdx.x;
    const int base = g * SPER;
    for (int i = t; i < SPER * 34; i += 256) {
        int row = i / 34, d = i - row * 34;
        sm[row * 36 + d] = msa[(size_t)base * 34 + i];
    }
    __syncthreads();
    if (t < SPER) smn[t] = norm34(&sm[t * 36]);
    __syncthreads();
    float q[34];
    load_q(obs, act, t, q);
    float best = __builtin_inff();
#pragma unroll
    for (int j = 0; j < SPER; ++j) {
        float s = fmaf(-2.f, dot34_v4((const float4*)&sm[j * 36], q), smn[j]);
        best = fminf(best, s);
    }
    minima[(size_t)t * SBLK + g] = best;          // transposed: k_tau coalesced
}

// --- kernel 0b: tau = 10th-smallest slice-min; pack A-frags; zero cursors ---
__global__ __launch_bounds__(64) void k_tau(const float* __restrict__ minima,
                                            const float* __restrict__ obs,
                                            const float* __restrict__ act,
                                            v8s* __restrict__ afrag,
                                            int* __restrict__ cursor) {
    __shared__ __align__(16) unsigned short qs[48];
    const int b = blockIdx.x, lane = threadIdx.x;
    if (b == 0 && lane == 0) { cursor[0] = 0; cursor[1] = 0; }
    float v[16];
#pragma unroll
    for (int k = 0; k < 16; ++k) v[k] = minima[(size_t)b * SBLK + lane + 64 * k];
    float last = 0.f;
    for (int r = 0; r < TOPK; ++r) {
        float lm = v[0]; int la = 0;
#pragma unroll
        for (int k = 1; k < 16; ++k) { if (v[k] < lm) { lm = v[k]; la = k; } }
        float wm = lm;
        for (int off = 32; off; off >>= 1) wm = fminf(wm, __shfl_xor(wm, off));
        unsigned long long msk = __ballot(lm == wm);
        int first = (int)__builtin_ctzll(msk);
        if (lane == first) {
#pragma unroll
            for (int k = 0; k < 16; ++k) { if (k == la) v[k] = __builtin_inff(); }
        }
        last = wm;   // wave-uniform
    }
    // q-hat = [q(34), -0.5, (tau+MARGIN)/2, 0..0] as bf16 in LDS
    float val = 0.f;
    if (lane < 32)       val = obs[b * 32 + lane];
    else if (lane < 34)  val = act[b * 2 + (lane - 32)];
    else if (lane == 34) val = -0.5f;
    else if (lane == 35) val = 0.5f * (last + MARGIN);
    if (lane < 48) qs[lane] = (lane < 36) ? f2bf(val) : (unsigned short)0;
    __syncthreads();
    // pack A-frags: chunk (s,half) = q-hat shorts [s*16+half*8 .. +8]
    // dest lane-id in a filter wave = half*32 + mrow, query row = qt*32+mrow
    if (lane < 6) {
        int s = lane >> 1, half = lane & 1;
        int qt = b >> 5, mrow = b & 31;
        v8s frag = *(const v8s*)&qs[s * 16 + half * 8];
        afrag[(qt * 3 + s) * 64 + half * 32 + mrow] = frag;
    }
}

// --- kernel 1: MFMA bf16 filter; async fp32 staging; A-frags from global ----
__global__ __launch_bounds__(256, 5) void k_filter(const float* __restrict__ msa,
                                                   const v8s* __restrict__ afrag,
                                                   int* __restrict__ cursor,
                                                   unsigned* __restrict__ pbuf,
                                                   int* __restrict__ posq) {
    __shared__ __align__(16) float lmf[128 * 34];            // 17408 B raw fp32 rows
    __shared__ int lcount[NB];                               // 1024 B
    __shared__ int lcand[NB * LCAP];                         // 8192 B
    __shared__ int gbase;
    const int g = blockIdx.x, t = threadIdx.x;
    const int w = t >> 6, lane = t & 63;
    const int mrow = lane & 31, half = lane >> 5;
    lcount[t] = 0;
    for (int c = g; c < NCHUNK; c += FBLK) {
        const int lo = c * 128;
        __syncthreads();                       // lmf reuse (covers lcount init on iter 0)
        if (lo + 128 <= NPTS) {
            // async stage 128 rows x 136 B = 17 x 1024-B segments
            const char* src = (const char*)(msa + (size_t)lo * 34);
            char* dst = (char*)lmf;
            for (int seg = w; seg < 17; seg += 4)
                async_copy16(dst + seg * 1024 + lane * 16, src + seg * 1024 + lane * 16);
        } else {                               // tail chunk (block-uniform branch)
            const int valid = NPTS - lo;       // 32
            for (int i = t; i < 128 * 34; i += 256) lmf[i] = 0.f;
            __syncthreads();
            for (int i = t; i < valid * 34; i += 256) lmf[i] = msa[(size_t)lo * 34 + i];
        }
        __syncthreads();                       // drains vmcnt for global_load_lds
        // B-frag build from this lane's fp32 row; hw cvt_pk (RNE, same as f2bf)
        const float* myrow = &lmf[(w * 32 + mrow) * 34];
        const int p = lo + w * 32 + mrow;
        unsigned pk[17];
        float n0 = 0.f, n1 = 0.f;
#pragma unroll
        for (int i = 0; i < 17; ++i) {
            float2 f2 = *(const float2*)(myrow + 2 * i);     // 8-B aligned
            __hip_bfloat162 b2 = __float22bfloat162_rn(f2);
            unsigned u = *(unsigned*)&b2;                    // lo short = f2.x
            pk[i] = u;
            float r0 = bf2f((unsigned short)(u & 0xFFFFu));
            float r1 = bf2f((unsigned short)(u >> 16));
            n0 = fmaf(r0, r0, n0);
            n1 = fmaf(r1, r1, n1);
        }
        float nrm = n0 + n1;
        if (p >= NPTS) nrm = 1e30f;            // invalid rows never pass
        union U { unsigned u[4]; v8s v; };
        U b0, b1, b2u;
#pragma unroll
        for (int i = 0; i < 4; ++i) { b0.u[i] = pk[half * 4 + i]; b1.u[i] = pk[8 + half * 4 + i]; }
        b2u.u[0] = 0; b2u.u[1] = 0; b2u.u[2] = 0; b2u.u[3] = 0;
        if (half == 0) {
            b2u.u[0] = pk[16];                               // m32, m33
            b2u.u[1] = (unsigned)f2bf(nrm) | (0x3F80u << 16); // nrm (k=34), 1.0 (k=35)
        }
        const v8s B0 = b0.v, B1 = b1.v, B2 = b2u.v;
#pragma unroll
        for (int qt = 0; qt < 8; ++qt) {
            v8s A0 = afrag[(qt * 3 + 0) * 64 + lane];        // coalesced, L1/L2-hot
            v8s A1 = afrag[(qt * 3 + 1) * 64 + lane];
            v8s A2 = afrag[(qt * 3 + 2) * 64 + lane];
            v16f acc;
#pragma unroll
            for (int i = 0; i < 16; ++i) acc[i] = 0.f;
            acc = __builtin_amdgcn_mfma_f32_32x32x16_bf16(A0, B0, acc, 0, 0, 0);
            acc = __builtin_amdgcn_mfma_f32_32x32x16_bf16(A1, B1, acc, 0, 0, 0);
            acc = __builtin_amdgcn_mfma_f32_32x32x16_bf16(A2, B2, acc, 0, 0, 0);
            unsigned hm = 0;
#pragma unroll
            for (int r = 0; r < 16; ++r) hm |= (acc[r] >= 0.f) ? (1u << r) : 0u;
            while (hm) {                       // rare per lane
                int r = __builtin_ctz(hm);
                hm &= hm - 1;
                int qq = qt * 32 + (r & 3) + 8 * (r >> 2) + 4 * half;
                int slot = atomicAdd(&lcount[qq], 1);
                if (slot < LCAP) {
                    lcand[qq * LCAP + slot] = p;
                } else {                       // SAFE overflow: side region
                    int dg = atomicAdd(cursor + 1, 1);
                    if (dg < OCAP) pbuf[PMAIN + dg] = ((unsigned)qq << 19) | (unsigned)p;
                }
            }
        }
    }
    __syncthreads();
    // flush: prefix-scan -> ONE cursor atomic -> compacted writes + pos table
    int n = lcount[t];
    if (n > LCAP) n = LCAP;
    lcount[t] = n;
    __syncthreads();
    for (int off = 1; off < 256; off <<= 1) {  // Hillis-Steele inclusive scan
        int v = (t >= off) ? lcount[t - off] : 0;
        __syncthreads();
        lcount[t] += v;
        __syncthreads();
    }
    int base_l = lcount[t] - n;
    if (t == 255) gbase = atomicAdd(cursor, lcount[255]);
    __syncthreads();
    int start = gbase + base_l;
    if (start >= PMAIN) { start = 0; n = 0; }
    else if (start + n > PMAIN) n = PMAIN - start;
    posq[g * NB + t] = start | (n << 20);      // coalesced, no atomic
    for (int i = 0; i < n; ++i)
        pbuf[start + i] = (unsigned)lcand[t * LCAP + i];
}

// --- kernel 2: scan-compact my segments, exact fp32 rescore, top-10, softmax
__global__ __launch_bounds__(256) void k_final(const float* __restrict__ obs,
                                               const float* __restrict__ act,
                                               const float* __restrict__ msa,
                                               const unsigned* __restrict__ pbuf,
                                               const int* __restrict__ posq,
                                               const int* __restrict__ cursor,
                                               const float* __restrict__ memQ,
                                               float* __restrict__ out) {
    __shared__ float ls[CAP];
    __shared__ int   li[CAP];
    __shared__ int   sc[NB];
    __shared__ int   lcnt;
    __shared__ float rs[4];
    __shared__ int   ri[4];
    __shared__ float sel_s[TOPK];
    __shared__ int   sel_i[TOPK];
    const int b = blockIdx.x, t = threadIdx.x;
    const int lane = t & 63, wid = t >> 6;
    // gather my 5 posq segments (FBLK = 5*256)
    int nk[5], pk5[5], tot = 0;
#pragma unroll
    for (int k = 0; k < 5; ++k) {
        int packed = posq[(size_t)(t + 256 * k) * NB + b];
        nk[k] = (packed >> 20) & 0xF;
        pk5[k] = packed & 0xFFFFF;
        tot += nk[k];
    }
    sc[t] = tot;
    __syncthreads();
    for (int off = 1; off < 256; off <<= 1) {  // prefix scan (no atomics)
        int v = (t >= off) ? sc[t - off] : 0;
        __syncthreads();
        sc[t] += v;
        __syncthreads();
    }
    int myoff = sc[t] - tot;
    if (t == 0) lcnt = (sc[255] > CAP) ? CAP : sc[255];
    __syncthreads();
#pragma unroll
    for (int k = 0; k < 5; ++k)
        for (int i = 0; i < nk[k]; ++i) {
            if (myoff < CAP) li[myoff] = (int)pbuf[pk5[k] + i];
            ++myoff;
        }
    // overflow region (normally empty)
    int novf = cursor[1];
    if (novf > OCAP) novf = OCAP;
    for (int j = t; j < novf; j += 256) {
        unsigned pr = pbuf[PMAIN + j];
        if ((int)(pr >> 19) == b) {
            int s = atomicAdd(&lcnt, 1);
            if (s < CAP) li[s] = (int)(pr & 0x7FFFFu);
        }
    }
    __syncthreads();
    int cnt = lcnt;
    if (cnt > CAP) cnt = CAP;
    float q[34];
    load_q(obs, act, b, q);
    for (int j = t; j < cnt; j += 256) {        // exact fp32 re-scores
        const float* row = msa + (size_t)li[j] * 34;
        ls[j] = fmaf(-2.f, dot34(row, q), norm34(row));
    }
    __syncthreads();
    for (int k = 0; k < TOPK; ++k) {
        float bs = __builtin_inff();
        int   bi = 0x7fffffff;
        for (int j = t; j < cnt; j += 256) {
            float s = ls[j]; int i = li[j];
            if (s < bs || (s == bs && i < bi)) { bs = s; bi = i; }
        }
        for (int off = 32; off; off >>= 1) {
            float s2 = __shfl_down(bs, off);
            int   i2 = __shfl_down(bi, off);
            if (s2 < bs || (s2 == bs && i2 < bi)) { bs = s2; bi = i2; }
        }
        if (lane == 0) { rs[wid] = bs; ri[wid] = bi; }
        __syncthreads();
        if (t == 0) {
            float fs = rs[0]; int fi = ri[0];
#pragma unroll
            for (int ww = 1; ww < 4; ++ww) {
                if (rs[ww] < fs || (rs[ww] == fs && ri[ww] < fi)) { fs = rs[ww]; fi = ri[ww]; }
            }
            sel_s[k] = fs; sel_i[k] = fi;
        }
        __syncthreads();
        const int win = sel_i[k];
        for (int j = t; j < cnt; j += 256) {
            if (li[j] == win) ls[j] = __builtin_inff();
        }
        __syncthreads();
    }
    if (t == 0) {
        float m = sel_s[TOPK - 1];
        float wsum = 0.f, acc = 0.f;
#pragma unroll
        for (int k = 0; k < TOPK; ++k) {
            if (sel_i[k] == 0x7fffffff) continue;
            float w2 = expf(sel_s[k] - m);
            wsum += w2;
            acc = fmaf(w2, memQ[sel_i[k]], acc);
        }
        out[b] = acc / wsum;
    }
}

extern "C" void kernel_launch(void* const* d_in, const int* in_sizes, int n_in,
                              void* d_out, int out_size, void* d_ws, size_t ws_size,
                              hipStream_t stream) {
    const float* obs = (const float*)d_in[0];   // [256,32]
    const float* act = (const float*)d_in[1];   // [256,2]
    const float* msa = (const float*)d_in[2];   // [500000,34]
    const float* mq  = (const float*)d_in[3];   // [500000,1]
    float* out = (float*)d_out;                 // [256]

    char* ws = (char*)d_ws;
    int*      cursor = (int*)ws;                            // 8 B
    v8s*      afrag  = (v8s*)(ws + 256);                    // 24576 B
    float*    minima = (float*)(ws + 32768);                // 1 MB (256 x 1024)
    int*      posq   = (int*)(ws + 32768 + 1048576);        // 1310720 B (1280 x 256)
    unsigned* pbuf   = (unsigned*)(ws + 32768 + 1048576 + 1310720); // 1703936 B
    // total ws use ~3.9 MB

    k_sample<<<SBLK, 256, 0, stream>>>(obs, act, msa, minima);
    k_tau   <<<NB, 64, 0, stream>>>(minima, obs, act, afrag, cursor);
    k_filter<<<FBLK, 256, 0, stream>>>(msa, afrag, cursor, pbuf, posq);
    k_final <<<NB, 256, 0, stream>>>(obs, act, msa, pbuf, posq, cursor, mq, out);
}

// Round 7
// 217.080 us; speedup vs baseline: 1.0720x; 1.0720x over previous
//
#include <hip/hip_runtime.h>
#include <hip/hip_bf16.h>
#include <math.h>

#define NPTS   500000
#define NB     256
#define TOPK   10
#define CAP    2048        // per-query candidate cap in k_final
#define SBLK   1024        // sample slices
#define SPER   16          // points per slice -> 16384-pt sample
#define MARGIN 2.0f        // bf16 worst-case score err ~0.5; 4x headroom
#define FBLK   1280        // k_filter grid (= 5 * 256 for k_final gather)
#define NCHUNK 3907        // ceil(NPTS/128)
#define LCAP   8           // per-(block,query) local cap; overflow safe-path
#define PMAIN  393216      // main pair region (dwords) < 2^20
#define OCAP   32768       // overflow pair region (dwords)

typedef short v4s  __attribute__((ext_vector_type(4)));
typedef short v8s  __attribute__((ext_vector_type(8)));
typedef float v16f __attribute__((ext_vector_type(16)));

__device__ __forceinline__ unsigned short f2bf(float f) {   // RNE
    unsigned u = __float_as_uint(f);
    unsigned r = u + 0x7FFFu + ((u >> 16) & 1u);
    return (unsigned short)(r >> 16);
}
__device__ __forceinline__ float bf2f(unsigned short h) {
    return __uint_as_float(((unsigned)h) << 16);
}

// async 16-B global->LDS (wave-uniform base + lane*16 contiguous pattern)
__device__ __forceinline__ void async_copy16(void* lds, const void* g) {
    __builtin_amdgcn_global_load_lds(
        (const __attribute__((address_space(1))) unsigned*)g,
        (__attribute__((address_space(3))) unsigned*)lds, 16, 0, 0);
}

// --- exact fp32 pieces: bitwise-identical order in k_sample and k_final -----
__device__ __forceinline__ float norm34(const float* __restrict__ r) {
    float a0 = 0.f, a1 = 0.f, a2 = 0.f, a3 = 0.f;
#pragma unroll
    for (int d = 0; d < 32; d += 4) {
        a0 = fmaf(r[d + 0], r[d + 0], a0);
        a1 = fmaf(r[d + 1], r[d + 1], a1);
        a2 = fmaf(r[d + 2], r[d + 2], a2);
        a3 = fmaf(r[d + 3], r[d + 3], a3);
    }
    a0 = fmaf(r[32], r[32], a0);
    a1 = fmaf(r[33], r[33], a1);
    return (a0 + a1) + (a2 + a3);
}
__device__ __forceinline__ float dot34(const float* __restrict__ r, const float* q) {
    float a0 = 0.f, a1 = 0.f, a2 = 0.f, a3 = 0.f;
#pragma unroll
    for (int d = 0; d < 32; d += 4) {
        a0 = fmaf(r[d + 0], q[d + 0], a0);
        a1 = fmaf(r[d + 1], q[d + 1], a1);
        a2 = fmaf(r[d + 2], q[d + 2], a2);
        a3 = fmaf(r[d + 3], q[d + 3], a3);
    }
    a0 = fmaf(r[32], q[32], a0);
    a1 = fmaf(r[33], q[33], a1);
    return (a0 + a1) + (a2 + a3);
}
// float4 LDS variant, IDENTICAL fma order -> bitwise-equal s
__device__ __forceinline__ float dot34_v4(const float4* __restrict__ r4, const float* q) {
    float a0 = 0.f, a1 = 0.f, a2 = 0.f, a3 = 0.f;
#pragma unroll
    for (int dp = 0; dp < 8; ++dp) {
        float4 v = r4[dp];
        a0 = fmaf(v.x, q[4 * dp + 0], a0);
        a1 = fmaf(v.y, q[4 * dp + 1], a1);
        a2 = fmaf(v.z, q[4 * dp + 2], a2);
        a3 = fmaf(v.w, q[4 * dp + 3], a3);
    }
    float2 t = *(const float2*)(r4 + 8);
    a0 = fmaf(t.x, q[32], a0);
    a1 = fmaf(t.y, q[33], a1);
    return (a0 + a1) + (a2 + a3);
}
__device__ __forceinline__ void load_q(const float* __restrict__ obs,
                                       const float* __restrict__ act, int b, float* q) {
#pragma unroll
    for (int d = 0; d < 32; ++d) q[d] = obs[b * 32 + d];
    q[32] = act[b * 2 + 0];
    q[33] = act[b * 2 + 1];
}

// --- kernel 0a: per-(query, 16-pt slice) min of s; minima transposed --------
__global__ __launch_bounds__(256, 4) void k_sample(const float* __restrict__ obs,
                                                   const float* __restrict__ act,
                                                   const float* __restrict__ msa,
                                                   float* __restrict__ minima) {
    __shared__ __align__(16) float sm[SPER * 36];
    __shared__ float smn[SPER];
    const int g = blockIdx.x, t = threadIdx.x;
    const int base = g * SPER;
    for (int i = t; i < SPER * 34; i += 256) {
        int row = i / 34, d = i - row * 34;
        sm[row * 36 + d] = msa[(size_t)base * 34 + i];
    }
    __syncthreads();
    if (t < SPER) smn[t] = norm34(&sm[t * 36]);
    __syncthreads();
    float q[34];
    load_q(obs, act, t, q);
    float best = __builtin_inff();
#pragma unroll
    for (int j = 0; j < SPER; ++j) {
        float s = fmaf(-2.f, dot34_v4((const float4*)&sm[j * 36], q), smn[j]);
        best = fminf(best, s);
    }
    minima[(size_t)t * SBLK + g] = best;          // transposed: k_tau coalesced
}

// --- kernel 0b: tau = 10th-smallest slice-min; pack A-frags; zero cursors ---
__global__ __launch_bounds__(64) void k_tau(const float* __restrict__ minima,
                                            const float* __restrict__ obs,
                                            const float* __restrict__ act,
                                            v8s* __restrict__ afrag,
                                            int* __restrict__ cursor) {
    __shared__ __align__(16) unsigned short qs[48];
    const int b = blockIdx.x, lane = threadIdx.x;
    if (b == 0 && lane == 0) { cursor[0] = 0; cursor[1] = 0; }
    float v[16];
#pragma unroll
    for (int k = 0; k < 16; ++k) v[k] = minima[(size_t)b * SBLK + lane + 64 * k];
    float last = 0.f;
    for (int r = 0; r < TOPK; ++r) {
        float lm = v[0]; int la = 0;
#pragma unroll
        for (int k = 1; k < 16; ++k) { if (v[k] < lm) { lm = v[k]; la = k; } }
        float wm = lm;
        for (int off = 32; off; off >>= 1) wm = fminf(wm, __shfl_xor(wm, off));
        unsigned long long msk = __ballot(lm == wm);
        int first = (int)__builtin_ctzll(msk);
        if (lane == first) {
#pragma unroll
            for (int k = 0; k < 16; ++k) { if (k == la) v[k] = __builtin_inff(); }
        }
        last = wm;   // wave-uniform
    }
    // q-hat = [q(34), -0.5, (tau+MARGIN)/2, 0..0] as bf16 in LDS
    float val = 0.f;
    if (lane < 32)       val = obs[b * 32 + lane];
    else if (lane < 34)  val = act[b * 2 + (lane - 32)];
    else if (lane == 34) val = -0.5f;
    else if (lane == 35) val = 0.5f * (last + MARGIN);
    if (lane < 48) qs[lane] = (lane < 36) ? f2bf(val) : (unsigned short)0;
    __syncthreads();
    // pack A-frags: chunk (s,half) = q-hat shorts [s*16+half*8 .. +8]
    // dest lane-id in a filter wave = half*32 + mrow, query row = qt*32+mrow
    if (lane < 6) {
        int s = lane >> 1, half = lane & 1;
        int qt = b >> 5, mrow = b & 31;
        v8s frag = *(const v8s*)&qs[s * 16 + half * 8];
        afrag[(qt * 3 + s) * 64 + half * 32 + mrow] = frag;
    }
}

// --- kernel 1: MFMA bf16 filter; async fp32 staging; NO private arrays ------
__global__ __launch_bounds__(256, 4) void k_filter(const float* __restrict__ msa,
                                                   const v8s* __restrict__ afrag,
                                                   int* __restrict__ cursor,
                                                   unsigned* __restrict__ pbuf,
                                                   int* __restrict__ posq) {
    __shared__ __align__(16) float lmf[128 * 34];            // 17408 B raw fp32 rows
    __shared__ int lcount[NB];                               // 1024 B
    __shared__ int lcand[NB * LCAP];                         // 8192 B
    __shared__ int gbase;
    const int g = blockIdx.x, t = threadIdx.x;
    const int w = t >> 6, lane = t & 63;
    const int mrow = lane & 31, half = lane >> 5;
    lcount[t] = 0;
    for (int c = g; c < NCHUNK; c += FBLK) {
        const int lo = c * 128;
        __syncthreads();                       // lmf reuse (covers lcount init on iter 0)
        if (lo + 128 <= NPTS) {
            // async stage 128 rows x 136 B = 17 x 1024-B segments
            const char* src = (const char*)(msa + (size_t)lo * 34);
            char* dst = (char*)lmf;
            for (int seg = w; seg < 17; seg += 4)
                async_copy16(dst + seg * 1024 + lane * 16, src + seg * 1024 + lane * 16);
        } else {                               // tail chunk (block-uniform branch)
            const int valid = NPTS - lo;
            for (int i = t; i < 128 * 34; i += 256) lmf[i] = 0.f;
            __syncthreads();
            for (int i = t; i < valid * 34; i += 256) lmf[i] = msa[(size_t)lo * 34 + i];
        }
        __syncthreads();                       // drains vmcnt for global_load_lds
        // ---- B-frag build: runtime indexing ONLY via LDS pointers ----------
        const float* myrow = &lmf[(w * 32 + mrow) * 34];
        const int p = lo + w * 32 + mrow;
        // fp32 norm of the row (consumed immediately; no private array)
        float n0 = 0.f, n1 = 0.f;
#pragma unroll
        for (int i = 0; i < 17; ++i) {
            float2 f2 = *(const float2*)(myrow + 2 * i);
            n0 = fmaf(f2.x, f2.x, n0);
            n1 = fmaf(f2.y, f2.y, n1);
        }
        float nrm = n0 + n1;
        if (p >= NPTS) nrm = 1e30f;            // invalid rows never pass
        union U { unsigned u[4]; v8s v; };
        U b0, b1, b2u;
        const float* b0p = myrow + half * 8;   // runtime offset -> LDS addr (fine)
#pragma unroll
        for (int i = 0; i < 4; ++i) {          // compile-time union indices
            float2 f2 = *(const float2*)(b0p + 2 * i);
            __hip_bfloat162 h2 = __float22bfloat162_rn(f2);   // RNE pk cvt, lo=x
            b0.u[i] = *(unsigned*)&h2;
        }
        const float* b1p = myrow + 16 + half * 8;
#pragma unroll
        for (int i = 0; i < 4; ++i) {
            float2 f2 = *(const float2*)(b1p + 2 * i);
            __hip_bfloat162 h2 = __float22bfloat162_rn(f2);
            b1.u[i] = *(unsigned*)&h2;
        }
        b2u.u[0] = 0; b2u.u[1] = 0; b2u.u[2] = 0; b2u.u[3] = 0;
        if (half == 0) {
            float2 f2 = *(const float2*)(myrow + 32);         // m32, m33
            __hip_bfloat162 h2 = __float22bfloat162_rn(f2);
            b2u.u[0] = *(unsigned*)&h2;
            b2u.u[1] = (unsigned)f2bf(nrm) | (0x3F80u << 16); // nrm (k=34), 1.0 (k=35)
        }
        const v8s B0 = b0.v, B1 = b1.v, B2 = b2u.v;
#pragma unroll
        for (int qt = 0; qt < 8; ++qt) {
            v8s A0 = afrag[(qt * 3 + 0) * 64 + lane];        // coalesced, L1/L2-hot
            v8s A1 = afrag[(qt * 3 + 1) * 64 + lane];
            v8s A2 = afrag[(qt * 3 + 2) * 64 + lane];
            v16f acc;
#pragma unroll
            for (int i = 0; i < 16; ++i) acc[i] = 0.f;
            acc = __builtin_amdgcn_mfma_f32_32x32x16_bf16(A0, B0, acc, 0, 0, 0);
            acc = __builtin_amdgcn_mfma_f32_32x32x16_bf16(A1, B1, acc, 0, 0, 0);
            acc = __builtin_amdgcn_mfma_f32_32x32x16_bf16(A2, B2, acc, 0, 0, 0);
            unsigned hm = 0;
#pragma unroll
            for (int r = 0; r < 16; ++r) hm |= (acc[r] >= 0.f) ? (1u << r) : 0u;
            while (hm) {                       // rare per lane
                int r = __builtin_ctz(hm);
                hm &= hm - 1;
                int qq = qt * 32 + (r & 3) + 8 * (r >> 2) + 4 * half;
                int slot = atomicAdd(&lcount[qq], 1);
                if (slot < LCAP) {
                    lcand[qq * LCAP + slot] = p;
                } else {                       // SAFE overflow: side region
                    int dg = atomicAdd(cursor + 1, 1);
                    if (dg < OCAP) pbuf[PMAIN + dg] = ((unsigned)qq << 19) | (unsigned)p;
                }
            }
        }
    }
    __syncthreads();
    // flush: prefix-scan -> ONE cursor atomic -> compacted writes + pos table
    int n = lcount[t];
    if (n > LCAP) n = LCAP;
    lcount[t] = n;
    __syncthreads();
    for (int off = 1; off < 256; off <<= 1) {  // Hillis-Steele inclusive scan
        int v = (t >= off) ? lcount[t - off] : 0;
        __syncthreads();
        lcount[t] += v;
        __syncthreads();
    }
    int base_l = lcount[t] - n;
    if (t == 255) gbase = atomicAdd(cursor, lcount[255]);
    __syncthreads();
    int start = gbase + base_l;
    if (start >= PMAIN) { start = 0; n = 0; }
    else if (start + n > PMAIN) n = PMAIN - start;
    posq[g * NB + t] = start | (n << 20);      // coalesced, no atomic
    for (int i = 0; i < n; ++i)
        pbuf[start + i] = (unsigned)lcand[t * LCAP + i];
}

// --- kernel 2: scan-compact my segments, exact fp32 rescore, top-10, softmax
__global__ __launch_bounds__(256) void k_final(const float* __restrict__ obs,
                                               const float* __restrict__ act,
                                               const float* __restrict__ msa,
                                               const unsigned* __restrict__ pbuf,
                                               const int* __restrict__ posq,
                                               const int* __restrict__ cursor,
                                               const float* __restrict__ memQ,
                                               float* __restrict__ out) {
    __shared__ float ls[CAP];
    __shared__ int   li[CAP];
    __shared__ int   sc[NB];
    __shared__ int   lcnt;
    __shared__ float rs[4];
    __shared__ int   ri[4];
    __shared__ float sel_s[TOPK];
    __shared__ int   sel_i[TOPK];
    const int b = blockIdx.x, t = threadIdx.x;
    const int lane = t & 63, wid = t >> 6;
    // gather my 5 posq segments (FBLK = 5*256)
    int nk[5], pk5[5], tot = 0;
#pragma unroll
    for (int k = 0; k < 5; ++k) {
        int packed = posq[(size_t)(t + 256 * k) * NB + b];
        nk[k] = (packed >> 20) & 0xF;
        pk5[k] = packed & 0xFFFFF;
        tot += nk[k];
    }
    sc[t] = tot;
    __syncthreads();
    for (int off = 1; off < 256; off <<= 1) {  // prefix scan (no atomics)
        int v = (t >= off) ? sc[t - off] : 0;
        __syncthreads();
        sc[t] += v;
        __syncthreads();
    }
    int myoff = sc[t] - tot;
    if (t == 0) lcnt = (sc[255] > CAP) ? CAP : sc[255];
    __syncthreads();
#pragma unroll
    for (int k = 0; k < 5; ++k)
        for (int i = 0; i < nk[k]; ++i) {
            if (myoff < CAP) li[myoff] = (int)pbuf[pk5[k] + i];
            ++myoff;
        }
    // overflow region (normally empty)
    int novf = cursor[1];
    if (novf > OCAP) novf = OCAP;
    for (int j = t; j < novf; j += 256) {
        unsigned pr = pbuf[PMAIN + j];
        if ((int)(pr >> 19) == b) {
            int s = atomicAdd(&lcnt, 1);
            if (s < CAP) li[s] = (int)(pr & 0x7FFFFu);
        }
    }
    __syncthreads();
    int cnt = lcnt;
    if (cnt > CAP) cnt = CAP;
    float q[34];
    load_q(obs, act, b, q);
    for (int j = t; j < cnt; j += 256) {        // exact fp32 re-scores
        const float* row = msa + (size_t)li[j] * 34;
        ls[j] = fmaf(-2.f, dot34(row, q), norm34(row));
    }
    __syncthreads();
    for (int k = 0; k < TOPK; ++k) {
        float bs = __builtin_inff();
        int   bi = 0x7fffffff;
        for (int j = t; j < cnt; j += 256) {
            float s = ls[j]; int i = li[j];
            if (s < bs || (s == bs && i < bi)) { bs = s; bi = i; }
        }
        for (int off = 32; off; off >>= 1) {
            float s2 = __shfl_down(bs, off);
            int   i2 = __shfl_down(bi, off);
            if (s2 < bs || (s2 == bs && i2 < bi)) { bs = s2; bi = i2; }
        }
        if (lane == 0) { rs[wid] = bs; ri[wid] = bi; }
        __syncthreads();
        if (t == 0) {
            float fs = rs[0]; int fi = ri[0];
#pragma unroll
            for (int ww = 1; ww < 4; ++ww) {
                if (rs[ww] < fs || (rs[ww] == fs && ri[ww] < fi)) { fs = rs[ww]; fi = ri[ww]; }
            }
            sel_s[k] = fs; sel_i[k] = fi;
        }
        __syncthreads();
        const int win = sel_i[k];
        for (int j = t; j < cnt; j += 256) {
            if (li[j] == win) ls[j] = __builtin_inff();
        }
        __syncthreads();
    }
    if (t == 0) {
        float m = sel_s[TOPK - 1];
        float wsum = 0.f, acc = 0.f;
#pragma unroll
        for (int k = 0; k < TOPK; ++k) {
            if (sel_i[k] == 0x7fffffff) continue;
            float w2 = expf(sel_s[k] - m);
            wsum += w2;
            acc = fmaf(w2, memQ[sel_i[k]], acc);
        }
        out[b] = acc / wsum;
    }
}

extern "C" void kernel_launch(void* const* d_in, const int* in_sizes, int n_in,
                              void* d_out, int out_size, void* d_ws, size_t ws_size,
                              hipStream_t stream) {
    const float* obs = (const float*)d_in[0];   // [256,32]
    const float* act = (const float*)d_in[1];   // [256,2]
    const float* msa = (const float*)d_in[2];   // [500000,34]
    const float* mq  = (const float*)d_in[3];   // [500000,1]
    float* out = (float*)d_out;                 // [256]

    char* ws = (char*)d_ws;
    int*      cursor = (int*)ws;                            // 8 B
    v8s*      afrag  = (v8s*)(ws + 256);                    // 24576 B
    float*    minima = (float*)(ws + 32768);                // 1 MB (256 x 1024)
    int*      posq   = (int*)(ws + 32768 + 1048576);        // 1310720 B (1280 x 256)
    unsigned* pbuf   = (unsigned*)(ws + 32768 + 1048576 + 1310720); // 1703936 B
    // total ws use ~3.9 MB

    k_sample<<<SBLK, 256, 0, stream>>>(obs, act, msa, minima);
    k_tau   <<<NB, 64, 0, stream>>>(minima, obs, act, afrag, cursor);
    k_filter<<<FBLK, 256, 0, stream>>>(msa, afrag, cursor, pbuf, posq);
    k_final <<<NB, 256, 0, stream>>>(obs, act, msa, pbuf, posq, cursor, mq, out);
}

// Round 9
// 182.785 us; speedup vs baseline: 1.2732x; 1.1876x over previous
//
#include <hip/hip_runtime.h>
#include <math.h>

#define NPTS   500000
#define NB     256
#define TOPK   10
#define CAP    2048        // per-query candidate cap in k_final
#define SBLK   1024        // sample slices
#define SPER   16          // points per slice -> 16384-pt sample
#define MARGIN 2.0f        // bf16 worst-case score err ~0.5; 4x headroom
#define FPTS   256         // points per k_filter chunk
#define FBLK   977         // grid: 977 blocks x 2 chunks = 1954 = ceil(NPTS/256)
#define LCAP   8           // per-(block,query) local cap; overflow safe-path
#define MS     56          // shorts per LDS row (112 B: 16-B aligned, 4-way b128)
#define PMAIN  393216      // main pair region (dwords) < 2^20
#define OCAP   32768       // overflow pair region (dwords)

typedef short v4s  __attribute__((ext_vector_type(4)));
typedef short v8s  __attribute__((ext_vector_type(8)));
typedef float v16f __attribute__((ext_vector_type(16)));

__device__ __forceinline__ unsigned short f2bf(float f) {   // RNE
    unsigned u = __float_as_uint(f);
    unsigned r = u + 0x7FFFu + ((u >> 16) & 1u);
    return (unsigned short)(r >> 16);
}
__device__ __forceinline__ float bf2f(unsigned short h) {
    return __uint_as_float(((unsigned)h) << 16);
}

// --- exact fp32 pieces: bitwise-identical order in k_sample and k_final -----
__device__ __forceinline__ float norm34(const float* __restrict__ r) {
    float a0 = 0.f, a1 = 0.f, a2 = 0.f, a3 = 0.f;
#pragma unroll
    for (int d = 0; d < 32; d += 4) {
        a0 = fmaf(r[d + 0], r[d + 0], a0);
        a1 = fmaf(r[d + 1], r[d + 1], a1);
        a2 = fmaf(r[d + 2], r[d + 2], a2);
        a3 = fmaf(r[d + 3], r[d + 3], a3);
    }
    a0 = fmaf(r[32], r[32], a0);
    a1 = fmaf(r[33], r[33], a1);
    return (a0 + a1) + (a2 + a3);
}
__device__ __forceinline__ float dot34(const float* __restrict__ r, const float* q) {
    float a0 = 0.f, a1 = 0.f, a2 = 0.f, a3 = 0.f;
#pragma unroll
    for (int d = 0; d < 32; d += 4) {
        a0 = fmaf(r[d + 0], q[d + 0], a0);
        a1 = fmaf(r[d + 1], q[d + 1], a1);
        a2 = fmaf(r[d + 2], q[d + 2], a2);
        a3 = fmaf(r[d + 3], q[d + 3], a3);
    }
    a0 = fmaf(r[32], q[32], a0);
    a1 = fmaf(r[33], q[33], a1);
    return (a0 + a1) + (a2 + a3);
}
// float4 LDS variant, IDENTICAL fma order -> bitwise-equal s
__device__ __forceinline__ float dot34_v4(const float4* __restrict__ r4, const float* q) {
    float a0 = 0.f, a1 = 0.f, a2 = 0.f, a3 = 0.f;
#pragma unroll
    for (int dp = 0; dp < 8; ++dp) {
        float4 v = r4[dp];
        a0 = fmaf(v.x, q[4 * dp + 0], a0);
        a1 = fmaf(v.y, q[4 * dp + 1], a1);
        a2 = fmaf(v.z, q[4 * dp + 2], a2);
        a3 = fmaf(v.w, q[4 * dp + 3], a3);
    }
    float2 t = *(const float2*)(r4 + 8);
    a0 = fmaf(t.x, q[32], a0);
    a1 = fmaf(t.y, q[33], a1);
    return (a0 + a1) + (a2 + a3);
}
__device__ __forceinline__ void load_q(const float* __restrict__ obs,
                                       const float* __restrict__ act, int b, float* q) {
#pragma unroll
    for (int d = 0; d < 32; ++d) q[d] = obs[b * 32 + d];
    q[32] = act[b * 2 + 0];
    q[33] = act[b * 2 + 1];
}

// --- kernel 0a: per-(query, 16-pt slice) min of s; minima transposed --------
__global__ __launch_bounds__(256, 4) void k_sample(const float* __restrict__ obs,
                                                   const float* __restrict__ act,
                                                   const float* __restrict__ msa,
                                                   float* __restrict__ minima) {
    __shared__ __align__(16) float sm[SPER * 36];
    __shared__ float smn[SPER];
    const int g = blockIdx.x, t = threadIdx.x;
    const int base = g * SPER;
    for (int i = t; i < SPER * 34; i += 256) {
        int row = i / 34, d = i - row * 34;
        sm[row * 36 + d] = msa[(size_t)base * 34 + i];
    }
    __syncthreads();
    if (t < SPER) smn[t] = norm34(&sm[t * 36]);
    __syncthreads();
    float q[34];
    load_q(obs, act, t, q);
    float best = __builtin_inff();
#pragma unroll
    for (int j = 0; j < SPER; ++j) {
        float s = fmaf(-2.f, dot34_v4((const float4*)&sm[j * 36], q), smn[j]);
        best = fminf(best, s);
    }
    minima[(size_t)t * SBLK + g] = best;          // transposed: k_tau coalesced
}

// --- kernel 0b: tau = 10th-smallest slice-min; pack A-frags; zero cursors ---
__global__ __launch_bounds__(64) void k_tau(const float* __restrict__ minima,
                                            const float* __restrict__ obs,
                                            const float* __restrict__ act,
                                            v8s* __restrict__ afrag,
                                            int* __restrict__ cursor) {
    __shared__ __align__(16) unsigned short qs[48];
    const int b = blockIdx.x, lane = threadIdx.x;
    if (b == 0 && lane == 0) { cursor[0] = 0; cursor[1] = 0; }
    float v[16];
#pragma unroll
    for (int k = 0; k < 16; ++k) v[k] = minima[(size_t)b * SBLK + lane + 64 * k];
    float last = 0.f;
    for (int r = 0; r < TOPK; ++r) {
        float lm = v[0]; int la = 0;
#pragma unroll
        for (int k = 1; k < 16; ++k) { if (v[k] < lm) { lm = v[k]; la = k; } }
        float wm = lm;
        for (int off = 32; off; off >>= 1) wm = fminf(wm, __shfl_xor(wm, off));
        unsigned long long msk = __ballot(lm == wm);
        int first = (int)__builtin_ctzll(msk);
        if (lane == first) {
#pragma unroll
            for (int k = 0; k < 16; ++k) { if (k == la) v[k] = __builtin_inff(); }
        }
        last = wm;   // wave-uniform
    }
    // q-hat = [q(34), -0.5, (tau+MARGIN)/2, 0..0] as bf16 in LDS
    float val = 0.f;
    if (lane < 32)       val = obs[b * 32 + lane];
    else if (lane < 34)  val = act[b * 2 + (lane - 32)];
    else if (lane == 34) val = -0.5f;
    else if (lane == 35) val = 0.5f * (last + MARGIN);
    if (lane < 48) qs[lane] = (lane < 36) ? f2bf(val) : (unsigned short)0;
    __syncthreads();
    // pack A-frags: chunk (s,half) = q-hat shorts [s*16+half*8 .. +8]
    // dest lane-id in a filter wave = half*32 + mrow, query row = qt*32+mrow
    if (lane < 6) {
        int s = lane >> 1, half = lane & 1;
        int qt = b >> 5, mrow = b & 31;
        v8s frag = *(const v8s*)&qs[s * 16 + half * 8];
        afrag[(qt * 3 + s) * 64 + half * 32 + mrow] = frag;
    }
}

// --- kernel 1: MFMA bf16 filter; ALL MFMA operands are pure loads -----------
__global__ __launch_bounds__(256, 4) void k_filter(const float* __restrict__ msa,
                                                   const v8s* __restrict__ afrag,
                                                   int* __restrict__ cursor,
                                                   unsigned* __restrict__ pbuf,
                                                   int* __restrict__ posq) {
    __shared__ __align__(16) unsigned short lm[FPTS * MS];   // 28672 B bf16 rows
    __shared__ int lcount[NB];                               // 1024 B
    __shared__ int lcand[NB * LCAP];                         // 8192 B
    __shared__ int gbase;
    const int g = blockIdx.x, t = threadIdx.x;
    const int w = t >> 6, lane = t & 63;
    const int mrow = lane & 31, half = lane >> 5;
    lcount[t] = 0;
#pragma unroll 1
    for (int rep = 0; rep < 2; ++rep) {
        const int c = g + rep * FBLK;           // 0..1953
        const int lo = c * FPTS;
        __syncthreads();                        // lm reuse (covers lcount on rep 0)
        // stage: fp32 global (coalesced float2) -> bf16 LDS rows (sw RNE pack)
        for (int i = t; i < FPTS * 17; i += 256) {
            int row = i / 17, dp = i - row * 17;
            int gp = lo + row;
            float2 v = make_float2(0.f, 0.f);
            if (gp < NPTS) v = *(const float2*)&msa[(size_t)gp * 34 + 2 * dp];
            unsigned pk = (unsigned)f2bf(v.x) | ((unsigned)f2bf(v.y) << 16);
            *(unsigned*)&lm[row * MS + 2 * dp] = pk;
        }
        __syncthreads();
        // norm pass: thread t owns row t; writes dims 34(|m|^2),35(1.0),36..47(0)
        {
            const unsigned short* mr = &lm[t * MS];
            float n0 = 0.f, n1 = 0.f;
#pragma unroll
            for (int dp = 0; dp < 17; ++dp) {
                ushort2 h = *(const ushort2*)(mr + 2 * dp);
                float f0 = bf2f(h.x), f1 = bf2f(h.y);
                n0 = fmaf(f0, f0, n0);
                n1 = fmaf(f1, f1, n1);
            }
            float nrm = n0 + n1;
            if (lo + t >= NPTS) nrm = 1e30f;    // invalid rows never pass
            unsigned nb = (unsigned)f2bf(nrm) | (0x3F80u << 16);  // |m|^2, 1.0
            *(unsigned*)&lm[t * MS + 34] = nb;
            *(unsigned*)&lm[t * MS + 36] = 0u;
            *(unsigned*)&lm[t * MS + 38] = 0u;
            *(unsigned*)&lm[t * MS + 40] = 0u;
            *(unsigned*)&lm[t * MS + 42] = 0u;
            *(unsigned*)&lm[t * MS + 44] = 0u;
            *(unsigned*)&lm[t * MS + 46] = 0u;
        }
        __syncthreads();
        // B frags: wave owns 64 points (2 tiles); 6x ds_read_b128, no construction
        const unsigned short* mr0 = &lm[(w * 64 + mrow) * MS + half * 8];
        const unsigned short* mr1 = &lm[(w * 64 + 32 + mrow) * MS + half * 8];
        const v8s B00 = *(const v8s*)(mr0);
        const v8s B01 = *(const v8s*)(mr0 + 16);
        const v8s B02 = *(const v8s*)(mr0 + 32);
        const v8s B10 = *(const v8s*)(mr1);
        const v8s B11 = *(const v8s*)(mr1 + 16);
        const v8s B12 = *(const v8s*)(mr1 + 32);
        const int p0 = lo + w * 64 + mrow;
#pragma unroll 1
        for (int qt = 0; qt < 8; ++qt) {
            v8s A0 = afrag[(qt * 3 + 0) * 64 + lane];        // L1-hot, coalesced
            v8s A1 = afrag[(qt * 3 + 1) * 64 + lane];
            v8s A2 = afrag[(qt * 3 + 2) * 64 + lane];
            v16f acc0, acc1;
#pragma unroll
            for (int i = 0; i < 16; ++i) { acc0[i] = 0.f; acc1[i] = 0.f; }
            acc0 = __builtin_amdgcn_mfma_f32_32x32x16_bf16(A0, B00, acc0, 0, 0, 0);
            acc0 = __builtin_amdgcn_mfma_f32_32x32x16_bf16(A1, B01, acc0, 0, 0, 0);
            acc0 = __builtin_amdgcn_mfma_f32_32x32x16_bf16(A2, B02, acc0, 0, 0, 0);
            acc1 = __builtin_amdgcn_mfma_f32_32x32x16_bf16(A0, B10, acc1, 0, 0, 0);
            acc1 = __builtin_amdgcn_mfma_f32_32x32x16_bf16(A1, B11, acc1, 0, 0, 0);
            acc1 = __builtin_amdgcn_mfma_f32_32x32x16_bf16(A2, B12, acc1, 0, 0, 0);
            unsigned hm0 = 0, hm1 = 0;
#pragma unroll
            for (int r = 0; r < 16; ++r) {
                hm0 |= (acc0[r] >= 0.f) ? (1u << r) : 0u;
                hm1 |= (acc1[r] >= 0.f) ? (1u << r) : 0u;
            }
            while (hm0) {                       // rare per lane
                int r = __builtin_ctz(hm0);
                hm0 &= hm0 - 1;
                int qq = qt * 32 + (r & 3) + 8 * (r >> 2) + 4 * half;
                int slot = atomicAdd(&lcount[qq], 1);
                if (slot < LCAP) lcand[qq * LCAP + slot] = p0;
                else {                          // SAFE overflow: side region
                    int dg = atomicAdd(cursor + 1, 1);
                    if (dg < OCAP) pbuf[PMAIN + dg] = ((unsigned)qq << 19) | (unsigned)p0;
                }
            }
            while (hm1) {
                int r = __builtin_ctz(hm1);
                hm1 &= hm1 - 1;
                int qq = qt * 32 + (r & 3) + 8 * (r >> 2) + 4 * half;
                int slot = atomicAdd(&lcount[qq], 1);
                if (slot < LCAP) lcand[qq * LCAP + slot] = p0 + 32;
                else {
                    int dg = atomicAdd(cursor + 1, 1);
                    if (dg < OCAP) pbuf[PMAIN + dg] = ((unsigned)qq << 19) | (unsigned)(p0 + 32);
                }
            }
        }
    }
    __syncthreads();
    // flush: prefix-scan -> ONE cursor atomic -> compacted writes + pos table
    int n = lcount[t];
    if (n > LCAP) n = LCAP;
    lcount[t] = n;
    __syncthreads();
    for (int off = 1; off < 256; off <<= 1) {   // Hillis-Steele inclusive scan
        int v = (t >= off) ? lcount[t - off] : 0;
        __syncthreads();
        lcount[t] += v;
        __syncthreads();
    }
    int base_l = lcount[t] - n;
    if (t == 255) gbase = atomicAdd(cursor, lcount[255]);
    __syncthreads();
    int start = gbase + base_l;
    if (start >= PMAIN) { start = 0; n = 0; }
    else if (start + n > PMAIN) n = PMAIN - start;
    posq[g * NB + t] = start | (n << 20);       // coalesced, no atomic
    for (int i = 0; i < n; ++i)
        pbuf[start + i] = (unsigned)lcand[t * LCAP + i];
}

// --- kernel 2: gather my segments, exact fp32 rescore, top-10, softmax ------
__global__ __launch_bounds__(256) void k_final(const float* __restrict__ obs,
                                               const float* __restrict__ act,
                                               const float* __restrict__ msa,
                                               const unsigned* __restrict__ pbuf,
                                               const int* __restrict__ posq,
                                               const int* __restrict__ cursor,
                                               const float* __restrict__ memQ,
                                               float* __restrict__ out) {
    __shared__ float ls[CAP];
    __shared__ int   li[CAP];
    __shared__ int   sc[NB];
    __shared__ int   lcnt;
    __shared__ float rs[4];
    __shared__ int   ri[4];
    __shared__ float sel_s[TOPK];
    __shared__ int   sel_i[TOPK];
    const int b = blockIdx.x, t = threadIdx.x;
    const int lane = t & 63, wid = t >> 6;
    // gather my posq segments (FBLK = 977 -> up to 4 per thread, fixed slots)
    int nk[4], pk4[4], tot = 0;
#pragma unroll
    for (int k = 0; k < 4; ++k) {
        int g = t + 256 * k;
        int packed = (g < FBLK) ? posq[(size_t)g * NB + b] : 0;
        nk[k] = (packed >> 20) & 0xF;
        pk4[k] = packed & 0xFFFFF;
        tot += nk[k];
    }
    sc[t] = tot;
    __syncthreads();
    for (int off = 1; off < 256; off <<= 1) {   // prefix scan (no atomics)
        int v = (t >= off) ? sc[t - off] : 0;
        __syncthreads();
        sc[t] += v;
        __syncthreads();
    }
    int myoff = sc[t] - tot;
    if (t == 0) lcnt = (sc[255] > CAP) ? CAP : sc[255];
    __syncthreads();
#pragma unroll
    for (int k = 0; k < 4; ++k)
        for (int i = 0; i < nk[k]; ++i) {
            if (myoff < CAP) li[myoff] = (int)pbuf[pk4[k] + i];
            ++myoff;
        }
    // overflow region (normally empty)
    int novf = cursor[1];
    if (novf > OCAP) novf = OCAP;
    for (int j = t; j < novf; j += 256) {
        unsigned pr = pbuf[PMAIN + j];
        if ((int)(pr >> 19) == b) {
            int s = atomicAdd(&lcnt, 1);
            if (s < CAP) li[s] = (int)(pr & 0x7FFFFu);
        }
    }
    __syncthreads();
    int cnt = lcnt;
    if (cnt > CAP) cnt = CAP;
    float q[34];
    load_q(obs, act, b, q);
    for (int j = t; j < cnt; j += 256) {        // exact fp32 re-scores
        const float* row = msa + (size_t)li[j] * 34;
        ls[j] = fmaf(-2.f, dot34(row, q), norm34(row));
    }
    __syncthreads();
    for (int k = 0; k < TOPK; ++k) {
        float bs = __builtin_inff();
        int   bi = 0x7fffffff;
        for (int j = t; j < cnt; j += 256) {
            float s = ls[j]; int i = li[j];
            if (s < bs || (s == bs && i < bi)) { bs = s; bi = i; }
        }
        for (int off = 32; off; off >>= 1) {
            float s2 = __shfl_down(bs, off);
            int   i2 = __shfl_down(bi, off);
            if (s2 < bs || (s2 == bs && i2 < bi)) { bs = s2; bi = i2; }
        }
        if (lane == 0) { rs[wid] = bs; ri[wid] = bi; }
        __syncthreads();
        if (t == 0) {
            float fs = rs[0]; int fi = ri[0];
#pragma unroll
            for (int ww = 1; ww < 4; ++ww) {
                if (rs[ww] < fs || (rs[ww] == fs && ri[ww] < fi)) { fs = rs[ww]; fi = ri[ww]; }
            }
            sel_s[k] = fs; sel_i[k] = fi;
        }
        __syncthreads();
        const int win = sel_i[k];
        for (int j = t; j < cnt; j += 256) {
            if (li[j] == win) ls[j] = __builtin_inff();
        }
        __syncthreads();
    }
    if (t == 0) {
        float m = sel_s[TOPK - 1];
        float wsum = 0.f, acc = 0.f;
#pragma unroll
        for (int k = 0; k < TOPK; ++k) {
            if (sel_i[k] == 0x7fffffff) continue;
            float w2 = expf(sel_s[k] - m);
            wsum += w2;
            acc = fmaf(w2, memQ[sel_i[k]], acc);
        }
        out[b] = acc / wsum;
    }
}

extern "C" void kernel_launch(void* const* d_in, const int* in_sizes, int n_in,
                              void* d_out, int out_size, void* d_ws, size_t ws_size,
                              hipStream_t stream) {
    const float* obs = (const float*)d_in[0];   // [256,32]
    const float* act = (const float*)d_in[1];   // [256,2]
    const float* msa = (const float*)d_in[2];   // [500000,34]
    const float* mq  = (const float*)d_in[3];   // [500000,1]
    float* out = (float*)d_out;                 // [256]

    char* ws = (char*)d_ws;
    int*      cursor = (int*)ws;                            // 8 B
    v8s*      afrag  = (v8s*)(ws + 256);                    // 24576 B
    float*    minima = (float*)(ws + 32768);                // 1 MB (256 x 1024)
    int*      posq   = (int*)(ws + 32768 + 1048576);        // 1000448 B (977 x 256)
    unsigned* pbuf   = (unsigned*)(ws + 32768 + 1048576 + 1000448); // 1703936 B
    // total ws use ~3.7 MB

    k_sample<<<SBLK, 256, 0, stream>>>(obs, act, msa, minima);
    k_tau   <<<NB, 64, 0, stream>>>(minima, obs, act, afrag, cursor);
    k_filter<<<FBLK, 256, 0, stream>>>(msa, afrag, cursor, pbuf, posq);
    k_final <<<NB, 256, 0, stream>>>(obs, act, msa, pbuf, posq, cursor, mq, out);
}